// Round 3
// baseline (127.179 us; speedup 1.0000x reference)
//
#include <hip/hip_runtime.h>
#include <math.h>

#define NJ  32        // j-axis chunks per direction
#define CB  256       // chamfer block size (threads)
#define IPT 4         // x-points per thread

// ---------------------------------------------------------------------------
// device helper: rigid transform (v+t) then Rx, Ry, Rz — EXACT op order of ref
// ---------------------------------------------------------------------------
__device__ __forceinline__ void xform(float x, float y, float z,
                                      float tx, float ty, float tz,
                                      float cx, float sx, float cy, float sy,
                                      float cz, float sz,
                                      float& ox, float& oy, float& oz)
{
    x += tx; y += ty; z += tz;
    float x1 = x;
    float y1 = cx*y - sx*z;
    float z1 = sx*y + cx*z;
    float x2 =  cy*x1 + sy*z1;
    float y2 = y1;
    float z2 = -sy*x1 + cy*z1;
    ox = cz*x2 - sz*y2;
    oy = sz*x2 + cz*y2;
    oz = z2;
}

// ---------------------------------------------------------------------------
// K1: p = Rz*Ry*Rx*(v + t) for all verts (the second output)
// ---------------------------------------------------------------------------
__global__ void k_transform(const float* __restrict__ verts,
                            const float* __restrict__ trans,
                            const float* __restrict__ ax,
                            const float* __restrict__ ay,
                            const float* __restrict__ az,
                            float* __restrict__ out, int V)
{
    int i = blockIdx.x * blockDim.x + threadIdx.x;
    if (i >= V) return;
    const float D2R = 0.017453292519943295f;
    float txr = ax[0]*D2R, tyr = ay[0]*D2R, tzr = az[0]*D2R;
    float cx = cosf(txr), sx = sinf(txr);
    float cy = cosf(tyr), sy = sinf(tyr);
    float cz = cosf(tzr), sz = sinf(tzr);
    float ox, oy, oz;
    xform(verts[3*i+0], verts[3*i+1], verts[3*i+2],
          trans[0], trans[1], trans[2], cx, sx, cy, sy, cz, sz, ox, oy, oz);
    out[3*i+0] = ox; out[3*i+1] = oy; out[3*i+2] = oz;
}

// ---------------------------------------------------------------------------
// K2: sample points + normals, both meshes in one launch (blockIdx.y = which).
// For the moving mesh (which==0) the transform is applied to the 3 gathered
// vertices inline (bitwise-identical to transforming first), so this kernel
// does NOT depend on k_transform -> graph-parallel.
// ptsS = (x,y,z, |p|^2) ; nrm = (nx,ny,nz,0)
// ---------------------------------------------------------------------------
__global__ void k_sample2(const float* __restrict__ vertsM, const int* __restrict__ facesM,
                          const int* __restrict__ fidxM, const float* __restrict__ uvM,
                          float4* __restrict__ ptsM, float4* __restrict__ nrmM,
                          const float* __restrict__ vertsF, const int* __restrict__ facesF,
                          const int* __restrict__ fidxF, const float* __restrict__ uvF,
                          float4* __restrict__ ptsF, float4* __restrict__ nrmF,
                          const float* __restrict__ trans,
                          const float* __restrict__ ax,
                          const float* __restrict__ ay,
                          const float* __restrict__ az, int N)
{
    int which = blockIdx.y;
    const float* verts = which ? vertsF : vertsM;
    const int*   faces = which ? facesF : facesM;
    const int*   fidx  = which ? fidxF  : fidxM;
    const float* uv    = which ? uvF    : uvM;
    float4* ptsS = which ? ptsF : ptsM;
    float4* nrm  = which ? nrmF : nrmM;

    int i = blockIdx.x * blockDim.x + threadIdx.x;
    if (i >= N) return;
    int f  = fidx[i];
    int i0 = faces[3*f+0], i1 = faces[3*f+1], i2 = faces[3*f+2];
    float v0x = verts[3*i0+0], v0y = verts[3*i0+1], v0z = verts[3*i0+2];
    float v1x = verts[3*i1+0], v1y = verts[3*i1+1], v1z = verts[3*i1+2];
    float v2x = verts[3*i2+0], v2y = verts[3*i2+1], v2z = verts[3*i2+2];

    if (!which) {
        const float D2R = 0.017453292519943295f;
        float txr = ax[0]*D2R, tyr = ay[0]*D2R, tzr = az[0]*D2R;
        float cx = cosf(txr), sx = sinf(txr);
        float cy = cosf(tyr), sy = sinf(tyr);
        float cz = cosf(tzr), sz = sinf(tzr);
        xform(v0x, v0y, v0z, trans[0], trans[1], trans[2], cx,sx,cy,sy,cz,sz, v0x,v0y,v0z);
        xform(v1x, v1y, v1z, trans[0], trans[1], trans[2], cx,sx,cy,sy,cz,sz, v1x,v1y,v1z);
        xform(v2x, v2y, v2z, trans[0], trans[1], trans[2], cx,sx,cy,sy,cz,sz, v2x,v2y,v2z);
    }

    float su = sqrtf(uv[2*i+0]);
    float vv = uv[2*i+1];
    float a = 1.0f - su;
    float b = su * (1.0f - vv);
    float c = su * vv;
    float px = a*v0x + b*v1x + c*v2x;
    float py = a*v0y + b*v1y + c*v2y;
    float pz = a*v0z + b*v1z + c*v2z;

    float e1x = v1x - v0x, e1y = v1y - v0y, e1z = v1z - v0z;
    float e2x = v2x - v0x, e2y = v2y - v0y, e2z = v2z - v0z;
    float nx = e1y*e2z - e1z*e2y;
    float ny = e1z*e2x - e1x*e2z;
    float nz = e1x*e2y - e1y*e2x;
    float nn = sqrtf(nx*nx + ny*ny + nz*nz) + 1e-8f;
    nx /= nn; ny /= nn; nz /= nn;

    ptsS[i] = make_float4(px, py, pz, px*px + py*py + pz*pz);
    nrm[i]  = make_float4(nx, ny, nz, 0.0f);
}

// ---------------------------------------------------------------------------
// K3: both chamfer directions, partial argmin per j-chunk.
// grid = (ceil(N/(CB*IPT)), NJ, 2).  dir=blockIdx.z: 0 = m->f, 1 = f->m.
// Inner loop argmins d' = |y|^2 - 2 x.y  (3-FMA chain); x.w added in epilogue
// so stored value equals |x|^2+|y|^2-2x.y.  Strict < = first-occurrence.
// ---------------------------------------------------------------------------
__global__ void k_cham2(const float4* __restrict__ Pm, const float4* __restrict__ Pf,
                        float* __restrict__ pval, int* __restrict__ pidx, int N)
{
    int dir = blockIdx.z;
    const float4* X = dir ? Pf : Pm;
    const float4* Y = dir ? Pm : Pf;
    float* pv = pval + (size_t)dir * NJ * N;
    int*   pi = pidx + (size_t)dir * NJ * N;

    __shared__ float4 tile[((10000 + NJ - 1) / NJ) + 8];
    int chunk = blockIdx.y;
    int j0 = (int)(((long long)N * chunk) / NJ);
    int j1 = (int)(((long long)N * (chunk + 1)) / NJ);
    int cnt = j1 - j0;
    for (int t = threadIdx.x; t < cnt; t += CB) tile[t] = Y[j0 + t];
    __syncthreads();

    int ibase = blockIdx.x * CB * IPT + threadIdx.x;

    float xs0[IPT], xs1[IPT], xs2[IPT], xw[IPT];
    #pragma unroll
    for (int p = 0; p < IPT; ++p) {
        int i = ibase + p * CB;
        float4 x = (i < N) ? X[i] : make_float4(0.f, 0.f, 0.f, 0.f);
        xs0[p] = -2.0f * x.x;
        xs1[p] = -2.0f * x.y;
        xs2[p] = -2.0f * x.z;
        xw[p]  = x.w;
    }
    float best[IPT]; int bi[IPT];
    #pragma unroll
    for (int p = 0; p < IPT; ++p) { best[p] = 3.4e38f; bi[p] = j0; }

    #pragma unroll 4
    for (int jj = 0; jj < cnt; ++jj) {
        float4 y = tile[jj];                     // wave-broadcast read
        #pragma unroll
        for (int p = 0; p < IPT; ++p) {
            float d = fmaf(xs0[p], y.x,
                      fmaf(xs1[p], y.y,
                      fmaf(xs2[p], y.z, y.w)));
            if (d < best[p]) { best[p] = d; bi[p] = j0 + jj; }
        }
    }
    #pragma unroll
    for (int p = 0; p < IPT; ++p) {
        int i = ibase + p * CB;
        if (i < N) {
            pv[(size_t)chunk*N + i] = best[p] + xw[p];
            pi[(size_t)chunk*N + i] = bi[p];
        }
    }
}

// ---------------------------------------------------------------------------
// K4: combine NJ partials per point, add normal-cosine term, block-reduce.
// ---------------------------------------------------------------------------
__global__ void k_combine(const float* __restrict__ pval, const int* __restrict__ pidx,
                          const float4* __restrict__ n_m, const float4* __restrict__ n_f,
                          float* __restrict__ partial, int N)
{
    int dir = blockIdx.y;
    const float* pv = pval + (size_t)dir * NJ * N;
    const int*   pi = pidx + (size_t)dir * NJ * N;

    int i = blockIdx.x * 256 + threadIdx.x;
    float term = 0.0f;
    if (i < N) {
        float best = pv[i]; int bi = pi[i];
        #pragma unroll
        for (int c = 1; c < NJ; ++c) {
            float v = pv[(size_t)c*N + i];
            if (v < best) { best = v; bi = pi[(size_t)c*N + i]; }
        }
        float4 a = dir ? n_f[i]  : n_m[i];
        float4 b = dir ? n_m[bi] : n_f[bi];
        term = best + 1.0f - fabsf(a.x*b.x + a.y*b.y + a.z*b.z);
    }
    __shared__ float red[256];
    red[threadIdx.x] = term;
    __syncthreads();
    for (int s = 128; s > 0; s >>= 1) {
        if (threadIdx.x < s) red[threadIdx.x] += red[threadIdx.x + s];
        __syncthreads();
    }
    if (threadIdx.x == 0) partial[dir * gridDim.x + blockIdx.x] = red[0];
}

// ---------------------------------------------------------------------------
// K5: final sum of per-block partials -> loss
// ---------------------------------------------------------------------------
__global__ void k_final(const float* __restrict__ partial, int nPart,
                        float* __restrict__ out, int N)
{
    __shared__ float red[256];
    float acc = 0.0f;
    for (int i = threadIdx.x; i < nPart; i += 256) acc += partial[i];
    red[threadIdx.x] = acc;
    __syncthreads();
    for (int s = 128; s > 0; s >>= 1) {
        if (threadIdx.x < s) red[threadIdx.x] += red[threadIdx.x + s];
        __syncthreads();
    }
    if (threadIdx.x == 0) out[0] = red[0] / (float)N;
}

// ---------------------------------------------------------------------------
extern "C" void kernel_launch(void* const* d_in, const int* in_sizes, int n_in,
                              void* d_out, int out_size, void* d_ws, size_t ws_size,
                              hipStream_t stream)
{
    const float* verts_mov = (const float*)d_in[0];
    const int*   faces_mov = (const int*)  d_in[1];
    const float* verts_fix = (const float*)d_in[2];
    const int*   faces_fix = (const int*)  d_in[3];
    const float* trans     = (const float*)d_in[4];
    const float* ax        = (const float*)d_in[5];
    const float* ay        = (const float*)d_in[6];
    const float* az        = (const float*)d_in[7];
    const int*   fidx_mov  = (const int*)  d_in[8];
    const float* uv_mov    = (const float*)d_in[9];
    const int*   fidx_fix  = (const int*)  d_in[10];
    const float* uv_fix    = (const float*)d_in[11];

    int V = in_sizes[0] / 3;
    int N = in_sizes[8];

    float* out = (float*)d_out;
    float* p   = out + 1;           // transformed verts region of output

    // workspace layout (floats)
    float*  ws      = (float*)d_ws;
    float4* ptsS_m  = (float4*)(ws + 0*4*N);
    float4* n_m     = (float4*)(ws + 1*4*N);
    float4* ptsS_f  = (float4*)(ws + 2*4*N);
    float4* n_f     = (float4*)(ws + 3*4*N);
    float*  pval    = ws + 16*N;                      // 2 * NJ * N floats
    int*    pidx    = (int*)(ws + 16*N + 2*NJ*N);     // 2 * NJ * N ints
    float*  partial = ws + 16*N + 4*NJ*N;             // small

    // independent graph roots: k_transform and k_sample2
    k_transform<<<(V + 255)/256, 256, 0, stream>>>(verts_mov, trans, ax, ay, az, p, V);

    dim3 gs((N + 255)/256, 2);
    k_sample2<<<gs, 256, 0, stream>>>(verts_mov, faces_mov, fidx_mov, uv_mov, ptsS_m, n_m,
                                      verts_fix, faces_fix, fidx_fix, uv_fix, ptsS_f, n_f,
                                      trans, ax, ay, az, N);

    dim3 gc((N + CB*IPT - 1)/(CB*IPT), NJ, 2);
    k_cham2<<<gc, CB, 0, stream>>>(ptsS_m, ptsS_f, pval, pidx, N);

    int GX = (N + 255)/256;
    dim3 gk(GX, 2);
    k_combine<<<gk, 256, 0, stream>>>(pval, pidx, n_m, n_f, partial, N);

    k_final<<<1, 256, 0, stream>>>(partial, 2*GX, out, N);
}

// Round 4
// 119.781 us; speedup vs baseline: 1.0618x; 1.0618x over previous
//
#include <hip/hip_runtime.h>
#include <math.h>

#define NJ  64        // j-axis chunks per direction
#define CB  256       // chamfer block size (threads)
#define IPT 4         // x-points per thread

// ---------------------------------------------------------------------------
// device helper: rigid transform (v+t) then Rx, Ry, Rz — EXACT op order of ref
// ---------------------------------------------------------------------------
__device__ __forceinline__ void xform(float x, float y, float z,
                                      float tx, float ty, float tz,
                                      float cx, float sx, float cy, float sy,
                                      float cz, float sz,
                                      float& ox, float& oy, float& oz)
{
    x += tx; y += ty; z += tz;
    float x1 = x;
    float y1 = cx*y - sx*z;
    float z1 = sx*y + cx*z;
    float x2 =  cy*x1 + sy*z1;
    float y2 = y1;
    float z2 = -sy*x1 + cy*z1;
    ox = cz*x2 - sz*y2;
    oy = sz*x2 + cz*y2;
    oz = z2;
}

// ---------------------------------------------------------------------------
// K1: fused transform (blocks [0,nbT)) + sample mov (nbT..nbT+nbS) +
//     sample fix (nbT+nbS..nbT+2*nbS).  1D grid, block-range dispatch.
// ptsS = (x,y,z,|p|^2) ; nrm = (nx,ny,nz,0)
// ---------------------------------------------------------------------------
__global__ void k_prep(const float* __restrict__ vertsM, const int* __restrict__ facesM,
                       const int* __restrict__ fidxM, const float* __restrict__ uvM,
                       float4* __restrict__ ptsM, float4* __restrict__ nrmM,
                       const float* __restrict__ vertsF, const int* __restrict__ facesF,
                       const int* __restrict__ fidxF, const float* __restrict__ uvF,
                       float4* __restrict__ ptsF, float4* __restrict__ nrmF,
                       const float* __restrict__ trans,
                       const float* __restrict__ ax,
                       const float* __restrict__ ay,
                       const float* __restrict__ az,
                       float* __restrict__ pOut,
                       int V, int N, int nbT, int nbS)
{
    const float D2R = 0.017453292519943295f;
    int b = blockIdx.x;

    if (b < nbT) {
        // ---- transform all verts (second output) ----
        int i = b * blockDim.x + threadIdx.x;
        if (i >= V) return;
        float txr = ax[0]*D2R, tyr = ay[0]*D2R, tzr = az[0]*D2R;
        float cx = cosf(txr), sx = sinf(txr);
        float cy = cosf(tyr), sy = sinf(tyr);
        float cz = cosf(tzr), sz = sinf(tzr);
        float ox, oy, oz;
        xform(vertsM[3*i+0], vertsM[3*i+1], vertsM[3*i+2],
              trans[0], trans[1], trans[2], cx, sx, cy, sy, cz, sz, ox, oy, oz);
        pOut[3*i+0] = ox; pOut[3*i+1] = oy; pOut[3*i+2] = oz;
        return;
    }

    int bb = b - nbT;
    int which = (bb >= nbS) ? 1 : 0;            // 0 = moving, 1 = fixed
    int bx = which ? bb - nbS : bb;
    int i = bx * blockDim.x + threadIdx.x;
    if (i >= N) return;

    const float* verts = which ? vertsF : vertsM;
    const int*   faces = which ? facesF : facesM;
    const int*   fidx  = which ? fidxF  : fidxM;
    const float* uv    = which ? uvF    : uvM;
    float4* ptsS = which ? ptsF : ptsM;
    float4* nrm  = which ? nrmF : nrmM;

    int f  = fidx[i];
    int i0 = faces[3*f+0], i1 = faces[3*f+1], i2 = faces[3*f+2];
    float v0x = verts[3*i0+0], v0y = verts[3*i0+1], v0z = verts[3*i0+2];
    float v1x = verts[3*i1+0], v1y = verts[3*i1+1], v1z = verts[3*i1+2];
    float v2x = verts[3*i2+0], v2y = verts[3*i2+1], v2z = verts[3*i2+2];

    if (!which) {
        float txr = ax[0]*D2R, tyr = ay[0]*D2R, tzr = az[0]*D2R;
        float cx = cosf(txr), sx = sinf(txr);
        float cy = cosf(tyr), sy = sinf(tyr);
        float cz = cosf(tzr), sz = sinf(tzr);
        xform(v0x,v0y,v0z, trans[0],trans[1],trans[2], cx,sx,cy,sy,cz,sz, v0x,v0y,v0z);
        xform(v1x,v1y,v1z, trans[0],trans[1],trans[2], cx,sx,cy,sy,cz,sz, v1x,v1y,v1z);
        xform(v2x,v2y,v2z, trans[0],trans[1],trans[2], cx,sx,cy,sy,cz,sz, v2x,v2y,v2z);
    }

    float su = sqrtf(uv[2*i+0]);
    float vv = uv[2*i+1];
    float a = 1.0f - su;
    float bq = su * (1.0f - vv);
    float c = su * vv;
    float px = a*v0x + bq*v1x + c*v2x;
    float py = a*v0y + bq*v1y + c*v2y;
    float pz = a*v0z + bq*v1z + c*v2z;

    float e1x = v1x - v0x, e1y = v1y - v0y, e1z = v1z - v0z;
    float e2x = v2x - v0x, e2y = v2y - v0y, e2z = v2z - v0z;
    float nx = e1y*e2z - e1z*e2y;
    float ny = e1z*e2x - e1x*e2z;
    float nz = e1x*e2y - e1y*e2x;
    float nn = sqrtf(nx*nx + ny*ny + nz*nz) + 1e-8f;
    nx /= nn; ny /= nn; nz /= nn;

    ptsS[i] = make_float4(px, py, pz, px*px + py*py + pz*pz);
    nrm[i]  = make_float4(nx, ny, nz, 0.0f);
}

// ---------------------------------------------------------------------------
// K2: both chamfer directions, partial argmin per j-chunk.
// grid = (ceil(N/(CB*IPT)), NJ, 2).  dir=blockIdx.z: 0 = m->f, 1 = f->m.
// Inner loop argmins d' = |y|^2 - 2 x.y (3-FMA chain); x.w added in epilogue.
// Strict < = numpy first-occurrence tie-break (chunks scanned ascending later).
// Partial stored as float2(dist, bitcast idx) for one-load combine.
// ---------------------------------------------------------------------------
__global__ void k_cham2(const float4* __restrict__ Pm, const float4* __restrict__ Pf,
                        float2* __restrict__ pvi, int N)
{
    int dir = blockIdx.z;
    const float4* X = dir ? Pf : Pm;
    const float4* Y = dir ? Pm : Pf;
    float2* out = pvi + (size_t)dir * NJ * N;

    __shared__ float4 tile[((10000 + NJ - 1) / NJ) + 8];
    int chunk = blockIdx.y;
    int j0 = (int)(((long long)N * chunk) / NJ);
    int j1 = (int)(((long long)N * (chunk + 1)) / NJ);
    int cnt = j1 - j0;
    for (int t = threadIdx.x; t < cnt; t += CB) tile[t] = Y[j0 + t];
    __syncthreads();

    int ibase = blockIdx.x * CB * IPT + threadIdx.x;

    float xs0[IPT], xs1[IPT], xs2[IPT], xw[IPT];
    #pragma unroll
    for (int p = 0; p < IPT; ++p) {
        int i = ibase + p * CB;
        float4 x = (i < N) ? X[i] : make_float4(0.f, 0.f, 0.f, 0.f);
        xs0[p] = -2.0f * x.x;
        xs1[p] = -2.0f * x.y;
        xs2[p] = -2.0f * x.z;
        xw[p]  = x.w;
    }
    float best[IPT]; int bi[IPT];
    #pragma unroll
    for (int p = 0; p < IPT; ++p) { best[p] = 3.4e38f; bi[p] = j0; }

    #pragma unroll 4
    for (int jj = 0; jj < cnt; ++jj) {
        float4 y = tile[jj];                     // wave-broadcast read
        #pragma unroll
        for (int p = 0; p < IPT; ++p) {
            float d = fmaf(xs0[p], y.x,
                      fmaf(xs1[p], y.y,
                      fmaf(xs2[p], y.z, y.w)));
            if (d < best[p]) { best[p] = d; bi[p] = j0 + jj; }
        }
    }
    #pragma unroll
    for (int p = 0; p < IPT; ++p) {
        int i = ibase + p * CB;
        if (i < N)
            out[(size_t)chunk*N + i] = make_float2(best[p] + xw[p],
                                                   __int_as_float(bi[p]));
    }
}

// ---------------------------------------------------------------------------
// K3: combine NJ partials per point (ascending chunk order -> numpy
// tie-break), add normal-cosine term, block-reduce to per-block partial sum.
// ---------------------------------------------------------------------------
__global__ void k_combine(const float2* __restrict__ pvi,
                          const float4* __restrict__ n_m, const float4* __restrict__ n_f,
                          float* __restrict__ partial, int N)
{
    int dir = blockIdx.y;
    const float2* base = pvi + (size_t)dir * NJ * N;

    int i = blockIdx.x * 256 + threadIdx.x;
    float term = 0.0f;
    if (i < N) {
        float2 v0 = base[i];
        float best = v0.x; int bi = __float_as_int(v0.y);
        #pragma unroll
        for (int c = 1; c < NJ; ++c) {
            float2 v = base[(size_t)c*N + i];
            if (v.x < best) { best = v.x; bi = __float_as_int(v.y); }
        }
        float4 a = dir ? n_f[i]  : n_m[i];
        float4 b = dir ? n_m[bi] : n_f[bi];
        term = best + 1.0f - fabsf(a.x*b.x + a.y*b.y + a.z*b.z);
    }
    __shared__ float red[256];
    red[threadIdx.x] = term;
    __syncthreads();
    for (int s = 128; s > 0; s >>= 1) {
        if (threadIdx.x < s) red[threadIdx.x] += red[threadIdx.x + s];
        __syncthreads();
    }
    if (threadIdx.x == 0) partial[dir * gridDim.x + blockIdx.x] = red[0];
}

// ---------------------------------------------------------------------------
// K4: final sum of per-block partials -> loss
// ---------------------------------------------------------------------------
__global__ void k_final(const float* __restrict__ partial, int nPart,
                        float* __restrict__ out, int N)
{
    __shared__ float red[256];
    float acc = 0.0f;
    for (int i = threadIdx.x; i < nPart; i += 256) acc += partial[i];
    red[threadIdx.x] = acc;
    __syncthreads();
    for (int s = 128; s > 0; s >>= 1) {
        if (threadIdx.x < s) red[threadIdx.x] += red[threadIdx.x + s];
        __syncthreads();
    }
    if (threadIdx.x == 0) out[0] = red[0] / (float)N;
}

// ---------------------------------------------------------------------------
extern "C" void kernel_launch(void* const* d_in, const int* in_sizes, int n_in,
                              void* d_out, int out_size, void* d_ws, size_t ws_size,
                              hipStream_t stream)
{
    const float* verts_mov = (const float*)d_in[0];
    const int*   faces_mov = (const int*)  d_in[1];
    const float* verts_fix = (const float*)d_in[2];
    const int*   faces_fix = (const int*)  d_in[3];
    const float* trans     = (const float*)d_in[4];
    const float* ax        = (const float*)d_in[5];
    const float* ay        = (const float*)d_in[6];
    const float* az        = (const float*)d_in[7];
    const int*   fidx_mov  = (const int*)  d_in[8];
    const float* uv_mov    = (const float*)d_in[9];
    const int*   fidx_fix  = (const int*)  d_in[10];
    const float* uv_fix    = (const float*)d_in[11];

    int V = in_sizes[0] / 3;
    int N = in_sizes[8];

    float* out = (float*)d_out;
    float* p   = out + 1;           // transformed verts region of output

    // workspace layout (floats)
    float*  ws      = (float*)d_ws;
    float4* ptsS_m  = (float4*)(ws + 0*4*N);
    float4* n_m     = (float4*)(ws + 1*4*N);
    float4* ptsS_f  = (float4*)(ws + 2*4*N);
    float4* n_f     = (float4*)(ws + 3*4*N);
    float2* pvi     = (float2*)(ws + 16*N);           // 2 * NJ * N float2
    float*  partial = ws + 16*N + 4*NJ*N;             // small

    int nbT = (V + 255) / 256;
    int nbS = (N + 255) / 256;
    k_prep<<<nbT + 2*nbS, 256, 0, stream>>>(verts_mov, faces_mov, fidx_mov, uv_mov,
                                            ptsS_m, n_m,
                                            verts_fix, faces_fix, fidx_fix, uv_fix,
                                            ptsS_f, n_f,
                                            trans, ax, ay, az, p, V, N, nbT, nbS);

    dim3 gc((N + CB*IPT - 1)/(CB*IPT), NJ, 2);
    k_cham2<<<gc, CB, 0, stream>>>(ptsS_m, ptsS_f, pvi, N);

    int GX = (N + 255)/256;
    dim3 gk(GX, 2);
    k_combine<<<gk, 256, 0, stream>>>(pvi, n_m, n_f, partial, N);

    k_final<<<1, 256, 0, stream>>>(partial, 2*GX, out, N);
}

// Round 6
// 118.687 us; speedup vs baseline: 1.0716x; 1.0092x over previous
//
#include <hip/hip_runtime.h>
#include <math.h>

#define NJ  64        // j-axis chunks per direction
#define CB  256       // chamfer block size (threads)
#define IPT 4         // x-points per thread

// ---------------------------------------------------------------------------
// device helper: rigid transform (v+t) then Rx, Ry, Rz — EXACT op order of ref
// ---------------------------------------------------------------------------
__device__ __forceinline__ void xform(float x, float y, float z,
                                      float tx, float ty, float tz,
                                      float cx, float sx, float cy, float sy,
                                      float cz, float sz,
                                      float& ox, float& oy, float& oz)
{
    x += tx; y += ty; z += tz;
    float x1 = x;
    float y1 = cx*y - sx*z;
    float z1 = sx*y + cx*z;
    float x2 =  cy*x1 + sy*z1;
    float y2 = y1;
    float z2 = -sy*x1 + cy*z1;
    ox = cz*x2 - sz*y2;
    oy = sz*x2 + cz*y2;
    oz = z2;
}

// ---------------------------------------------------------------------------
// K1: fused transform (blocks [0,nbT)) + sample mov + sample fix.
// Block 0 / thread 0 also zeroes out[0] (the loss accumulator; harness
// poisons d_out to 0xAA before every replay, and k_combine atomicAdds later
// in stream order).
// ---------------------------------------------------------------------------
__global__ void k_prep(const float* __restrict__ vertsM, const int* __restrict__ facesM,
                       const int* __restrict__ fidxM, const float* __restrict__ uvM,
                       float4* __restrict__ ptsM, float4* __restrict__ nrmM,
                       const float* __restrict__ vertsF, const int* __restrict__ facesF,
                       const int* __restrict__ fidxF, const float* __restrict__ uvF,
                       float4* __restrict__ ptsF, float4* __restrict__ nrmF,
                       const float* __restrict__ trans,
                       const float* __restrict__ ax,
                       const float* __restrict__ ay,
                       const float* __restrict__ az,
                       float* __restrict__ lossOut,
                       float* __restrict__ pOut,
                       int V, int N, int nbT, int nbS)
{
    const float D2R = 0.017453292519943295f;
    int b = blockIdx.x;

    if (b == 0 && threadIdx.x == 0) lossOut[0] = 0.0f;

    if (b < nbT) {
        // ---- transform all verts (second output) ----
        int i = b * blockDim.x + threadIdx.x;
        if (i >= V) return;
        float txr = ax[0]*D2R, tyr = ay[0]*D2R, tzr = az[0]*D2R;
        float cx = cosf(txr), sx = sinf(txr);
        float cy = cosf(tyr), sy = sinf(tyr);
        float cz = cosf(tzr), sz = sinf(tzr);
        float ox, oy, oz;
        xform(vertsM[3*i+0], vertsM[3*i+1], vertsM[3*i+2],
              trans[0], trans[1], trans[2], cx, sx, cy, sy, cz, sz, ox, oy, oz);
        pOut[3*i+0] = ox; pOut[3*i+1] = oy; pOut[3*i+2] = oz;
        return;
    }

    int bb = b - nbT;
    int which = (bb >= nbS) ? 1 : 0;            // 0 = moving, 1 = fixed
    int bx = which ? bb - nbS : bb;
    int i = bx * blockDim.x + threadIdx.x;
    if (i >= N) return;

    const float* verts = which ? vertsF : vertsM;
    const int*   faces = which ? facesF : facesM;
    const int*   fidx  = which ? fidxF  : fidxM;
    const float* uv    = which ? uvF    : uvM;
    float4* ptsS = which ? ptsF : ptsM;
    float4* nrm  = which ? nrmF : nrmM;

    int f  = fidx[i];
    int i0 = faces[3*f+0], i1 = faces[3*f+1], i2 = faces[3*f+2];
    float v0x = verts[3*i0+0], v0y = verts[3*i0+1], v0z = verts[3*i0+2];
    float v1x = verts[3*i1+0], v1y = verts[3*i1+1], v1z = verts[3*i1+2];
    float v2x = verts[3*i2+0], v2y = verts[3*i2+1], v2z = verts[3*i2+2];

    if (!which) {
        float txr = ax[0]*D2R, tyr = ay[0]*D2R, tzr = az[0]*D2R;
        float cx = cosf(txr), sx = sinf(txr);
        float cy = cosf(tyr), sy = sinf(tyr);
        float cz = cosf(tzr), sz = sinf(tzr);
        xform(v0x,v0y,v0z, trans[0],trans[1],trans[2], cx,sx,cy,sy,cz,sz, v0x,v0y,v0z);
        xform(v1x,v1y,v1z, trans[0],trans[1],trans[2], cx,sx,cy,sy,cz,sz, v1x,v1y,v1z);
        xform(v2x,v2y,v2z, trans[0],trans[1],trans[2], cx,sx,cy,sy,cz,sz, v2x,v2y,v2z);
    }

    float su = sqrtf(uv[2*i+0]);
    float vv = uv[2*i+1];
    float a = 1.0f - su;
    float bq = su * (1.0f - vv);
    float c = su * vv;
    float px = a*v0x + bq*v1x + c*v2x;
    float py = a*v0y + bq*v1y + c*v2y;
    float pz = a*v0z + bq*v1z + c*v2z;

    float e1x = v1x - v0x, e1y = v1y - v0y, e1z = v1z - v0z;
    float e2x = v2x - v0x, e2y = v2y - v0y, e2z = v2z - v0z;
    float nx = e1y*e2z - e1z*e2y;
    float ny = e1z*e2x - e1x*e2z;
    float nz = e1x*e2y - e1y*e2x;
    float nn = sqrtf(nx*nx + ny*ny + nz*nz) + 1e-8f;
    nx /= nn; ny /= nn; nz /= nn;

    ptsS[i] = make_float4(px, py, pz, px*px + py*py + pz*pz);
    nrm[i]  = make_float4(nx, ny, nz, 0.0f);
}

// ---------------------------------------------------------------------------
// K2: both chamfer directions, partial argmin per j-chunk.
// grid = (ceil(N/(CB*IPT)), NJ, 2).  dir=blockIdx.z: 0 = m->f, 1 = f->m.
// Inner loop argmins d' = |y|^2 - 2 x.y (3-FMA chain); x.w added in epilogue.
// Strict < = numpy first-occurrence tie-break (chunks scanned ascending later).
// Partial stored as float2(dist, bitcast idx).
// ---------------------------------------------------------------------------
__global__ void k_cham2(const float4* __restrict__ Pm, const float4* __restrict__ Pf,
                        float2* __restrict__ pvi, int N)
{
    int dir = blockIdx.z;
    const float4* X = dir ? Pf : Pm;
    const float4* Y = dir ? Pm : Pf;
    float2* out = pvi + (size_t)dir * NJ * N;

    __shared__ float4 tile[((10000 + NJ - 1) / NJ) + 8];
    int chunk = blockIdx.y;
    int j0 = (int)(((long long)N * chunk) / NJ);
    int j1 = (int)(((long long)N * (chunk + 1)) / NJ);
    int cnt = j1 - j0;
    for (int t = threadIdx.x; t < cnt; t += CB) tile[t] = Y[j0 + t];
    __syncthreads();

    int ibase = blockIdx.x * CB * IPT + threadIdx.x;

    float xs0[IPT], xs1[IPT], xs2[IPT], xw[IPT];
    #pragma unroll
    for (int p = 0; p < IPT; ++p) {
        int i = ibase + p * CB;
        float4 x = (i < N) ? X[i] : make_float4(0.f, 0.f, 0.f, 0.f);
        xs0[p] = -2.0f * x.x;
        xs1[p] = -2.0f * x.y;
        xs2[p] = -2.0f * x.z;
        xw[p]  = x.w;
    }
    float best[IPT]; int bi[IPT];
    #pragma unroll
    for (int p = 0; p < IPT; ++p) { best[p] = 3.4e38f; bi[p] = j0; }

    #pragma unroll 4
    for (int jj = 0; jj < cnt; ++jj) {
        float4 y = tile[jj];                     // wave-broadcast read
        #pragma unroll
        for (int p = 0; p < IPT; ++p) {
            float d = fmaf(xs0[p], y.x,
                      fmaf(xs1[p], y.y,
                      fmaf(xs2[p], y.z, y.w)));
            if (d < best[p]) { best[p] = d; bi[p] = j0 + jj; }
        }
    }
    #pragma unroll
    for (int p = 0; p < IPT; ++p) {
        int i = ibase + p * CB;
        if (i < N)
            out[(size_t)chunk*N + i] = make_float2(best[p] + xw[p],
                                                   __int_as_float(bi[p]));
    }
}

// ---------------------------------------------------------------------------
// K3: combine NJ partials per point (ascending chunk order -> numpy
// tie-break), add normal-cosine term, block-reduce, atomicAdd to loss.
// out[0] was zeroed by k_prep (stream-ordered before this kernel).
// ---------------------------------------------------------------------------
__global__ void k_combine(const float2* __restrict__ pvi,
                          const float4* __restrict__ n_m, const float4* __restrict__ n_f,
                          float* __restrict__ lossOut, float invN, int N)
{
    int dir = blockIdx.y;
    const float2* base = pvi + (size_t)dir * NJ * N;

    int i = blockIdx.x * 256 + threadIdx.x;
    float term = 0.0f;
    if (i < N) {
        float2 v0 = base[i];
        float best = v0.x; int bi = __float_as_int(v0.y);
        #pragma unroll
        for (int c = 1; c < NJ; ++c) {
            float2 v = base[(size_t)c*N + i];
            if (v.x < best) { best = v.x; bi = __float_as_int(v.y); }
        }
        float4 a = dir ? n_f[i]  : n_m[i];
        float4 b = dir ? n_m[bi] : n_f[bi];
        term = best + 1.0f - fabsf(a.x*b.x + a.y*b.y + a.z*b.z);
    }
    __shared__ float red[256];
    red[threadIdx.x] = term;
    __syncthreads();
    for (int s = 128; s > 0; s >>= 1) {
        if (threadIdx.x < s) red[threadIdx.x] += red[threadIdx.x + s];
        __syncthreads();
    }
    if (threadIdx.x == 0) atomicAdd(lossOut, red[0] * invN);
}

// ---------------------------------------------------------------------------
extern "C" void kernel_launch(void* const* d_in, const int* in_sizes, int n_in,
                              void* d_out, int out_size, void* d_ws, size_t ws_size,
                              hipStream_t stream)
{
    const float* verts_mov = (const float*)d_in[0];
    const int*   faces_mov = (const int*)  d_in[1];
    const float* verts_fix = (const float*)d_in[2];
    const int*   faces_fix = (const int*)  d_in[3];
    const float* trans     = (const float*)d_in[4];
    const float* ax        = (const float*)d_in[5];
    const float* ay        = (const float*)d_in[6];
    const float* az        = (const float*)d_in[7];
    const int*   fidx_mov  = (const int*)  d_in[8];
    const float* uv_mov    = (const float*)d_in[9];
    const int*   fidx_fix  = (const int*)  d_in[10];
    const float* uv_fix    = (const float*)d_in[11];

    int V = in_sizes[0] / 3;
    int N = in_sizes[8];

    float* out = (float*)d_out;
    float* p   = out + 1;           // transformed verts region of output

    // workspace layout (floats)
    float*  ws      = (float*)d_ws;
    float4* ptsS_m  = (float4*)(ws + 0*4*N);
    float4* n_m     = (float4*)(ws + 1*4*N);
    float4* ptsS_f  = (float4*)(ws + 2*4*N);
    float4* n_f     = (float4*)(ws + 3*4*N);
    float2* pvi     = (float2*)(ws + 16*N);           // 2 * NJ * N float2

    int nbT = (V + 255) / 256;
    int nbS = (N + 255) / 256;
    k_prep<<<nbT + 2*nbS, 256, 0, stream>>>(verts_mov, faces_mov, fidx_mov, uv_mov,
                                            ptsS_m, n_m,
                                            verts_fix, faces_fix, fidx_fix, uv_fix,
                                            ptsS_f, n_f,
                                            trans, ax, ay, az, out, p, V, N, nbT, nbS);

    dim3 gc((N + CB*IPT - 1)/(CB*IPT), NJ, 2);
    k_cham2<<<gc, CB, 0, stream>>>(ptsS_m, ptsS_f, pvi, N);

    int GX = (N + 255)/256;
    dim3 gk(GX, 2);
    k_combine<<<gk, 256, 0, stream>>>(pvi, n_m, n_f, out, 1.0f/(float)N, N);
}